// Round 4
// baseline (465.990 us; speedup 1.0000x reference)
//
#include <hip/hip_runtime.h>

// CrossAttention decode, algebraically collapsed (all fp32):
//   q[b,h,:]   = ((x1@We1+be1)@Wq+bq) head-sliced
//   u[b,h,c]   = sum_d WkT[h*64+d,c]*q[b,h,d]
//   w[b,h,i]   = sum_c u[b,h,c]*We2t[c,i]          (K-proj folded)
//   score[b,h,s] = x2[b,s,:].w[b,h,:]              (K-bias cancels in softmax)
//   a = softmax(score/8)
//   g[b,h,i]   = sum_s a[b,h,s]*x3[b,s,i]
//   G2[b,h,c]  = g@We2 + be2;  av = G2@Wv_h + bv;  out = av@Wo + bo
// R4 (this round): pipe accounting showed k_attn's largest pipe is LDS:
// phase A did 4096 ds_read_b128/CU (~20us) at only 8 FMA per 12cy read.
// Restructure phase A: wave = (head-quad wv&3, c4-half wv>>2); each wave
// reads HALF the tile (16 c4/kt) but computes 4 heads per read -> 32 FMA
// per read, phase-A LDS reads halved; q stays wave-uniform (s_load).
// Partial dots combined ONCE post-kt via 4KB LDS exchange (aliased into
// dead tile); softmax fully wave-local in waves 0-3 (old sm/sl exchange
// deleted); x3 prefetch issued before the final barrier (latency overlaps
// softmax drain). k_greduce2: float4 gp reads (was 4B/lane). Small kernels:
// unroll 8 for deeper W-load pipelines.
// Lessons: R1/R2 occupancy 21->81% and R3 bytes-in-flight gave ~0: k_attn is
// pipe/issue-bound, not latency/occupancy-bound. No per-element global
// atomics on hot paths; stride-33 float4 LDS conflict-free (measured ~0);
// harness reset (~170us) fixed overhead.

#define DIN 512
#define DD  1024
#define NH  16
#define HD  64
#define BB  16
#define SS  4096
#define NCH 64   // s-chunks; schunk = 64

__device__ __forceinline__ int wave_id() {
    return __builtin_amdgcn_readfirstlane((int)(threadIdx.x >> 6));
}

__device__ __forceinline__ void tile_transpose(const float* __restrict__ in,
                                               float* __restrict__ out,
                                               int R, int C, int rblk, int cblk) {
    __shared__ float tl[32][33];
    const int tx = threadIdx.x & 31, ty = threadIdx.x >> 5;  // ty 0..7
    const int c0 = cblk * 32, r0 = rblk * 32;
#pragma unroll
    for (int k = 0; k < 4; ++k)
        tl[ty + k * 8][tx] = in[(size_t)(r0 + ty + k * 8) * C + c0 + tx];
    __syncthreads();
#pragma unroll
    for (int k = 0; k < 4; ++k)
        out[(size_t)(c0 + ty + k * 8) * R + r0 + tx] = tl[tx][ty + k * 8];
}

// One fused prep dispatch: We2/Wk transposes + bias init of atomic targets.
__global__ __launch_bounds__(256) void k_prep(const float* __restrict__ We2,
                                              const float* __restrict__ Wk,
                                              const float* __restrict__ be1,
                                              const float* __restrict__ bq,
                                              const float* __restrict__ bv,
                                              const float* __restrict__ bo,
                                              float* __restrict__ We2t,
                                              float* __restrict__ WkT,
                                              float* __restrict__ x1e,
                                              float* __restrict__ qb,
                                              float* __restrict__ av,
                                              float* __restrict__ out) {
    const int bx = blockIdx.x;
    if (bx < 512) {
        tile_transpose(We2, We2t, DIN, DD, bx >> 5, bx & 31);
    } else if (bx < 1536) {
        const int lb = bx - 512;
        tile_transpose(Wk, WkT, DD, DD, lb >> 5, lb & 31);
    } else {
        const int b = bx - 1536;
#pragma unroll
        for (int k = 0; k < 4; ++k) {
            const int c = k * 256 + threadIdx.x;
            x1e[(size_t)b * DD + c] = be1[c];
            qb[(size_t)b * DD + c]  = bq[c];
            av[(size_t)b * DD + c]  = bv[c];
            out[(size_t)b * DD + c] = bo[c];
        }
    }
}

// out[r][c] (+)= sum_i in[r][i]*W[i][c] for 16 rows. grid (N/64, R/16, KS).
template <int K, int N, int KS, bool HASB>
__global__ __launch_bounds__(256) void k_bmv2(const float* __restrict__ in,
                                              const float* __restrict__ W,
                                              const float* __restrict__ bias,
                                              float* __restrict__ out) {
    const int l = threadIdx.x & 63;
    const int c = blockIdx.x * 64 + l;
    const int wv = wave_id();
    constexpr int KCH = K / KS;
    constexpr int SUB = KCH / 4;
    const float* inb = in + (size_t)blockIdx.y * 16 * K;  // uniform -> s_load
    float acc[16];
#pragma unroll
    for (int r = 0; r < 16; ++r) acc[r] = 0.f;
    const int i0 = blockIdx.z * KCH + wv * SUB;
#pragma unroll 8
    for (int i = i0; i < i0 + SUB; ++i) {
        const float wval = W[(size_t)i * N + c];  // coalesced 256B/wave
#pragma unroll
        for (int r = 0; r < 16; ++r) acc[r] += inb[(size_t)r * K + i] * wval;
    }
    __shared__ float red[4][16][64];
#pragma unroll
    for (int r = 0; r < 16; ++r) red[wv][r][l] = acc[r];
    __syncthreads();
#pragma unroll
    for (int k = 0; k < 4; ++k) {
        const int r = wv + k * 4;
        float v = red[0][r][l] + red[1][r][l] + red[2][r][l] + red[3][r][l];
        float* dst = out + ((size_t)blockIdx.y * 16 + r) * N + c;
        if (KS == 1) {
            if (HASB) v += bias[c];
            *dst = v;
        } else {
            atomicAdd(dst, v);
        }
    }
}

// u[b*16+h][c] = sum_d q[b][h*64+d]*WkT[h*64+d][c].  grid (1024/64, 16 h).
__global__ __launch_bounds__(256) void k_u2(const float* __restrict__ q,
                                            const float* __restrict__ WkT,
                                            float* __restrict__ u) {
    const int h = blockIdx.y;
    const int l = threadIdx.x & 63;
    const int c = blockIdx.x * 64 + l;
    const int wv = wave_id();
    float acc[16];
#pragma unroll
    for (int bb = 0; bb < 16; ++bb) acc[bb] = 0.f;
#pragma unroll 8
    for (int dk = 0; dk < 16; ++dk) {
        const int d = wv * 16 + dk;
        const float wval = WkT[(size_t)(h * HD + d) * DD + c];  // coalesced
#pragma unroll
        for (int bb = 0; bb < 16; ++bb)
            acc[bb] += q[(size_t)bb * DD + h * HD + d] * wval;  // s_load
    }
    __shared__ float red[4][16][64];
#pragma unroll
    for (int bb = 0; bb < 16; ++bb) red[wv][bb][l] = acc[bb];
    __syncthreads();
#pragma unroll
    for (int k = 0; k < 4; ++k) {
        const int bb = wv + k * 4;
        float v = red[0][bb][l] + red[1][bb][l] + red[2][bb][l] + red[3][bb][l];
        u[((size_t)bb * NH + h) * DD + c] = v;
    }
}

// Fused scores+softmax+PV: grid (NCH=64, 16 b), block 512 (8 waves).
// Phase A: wave = (head-quad hq=wv&3, c4-half ch2=wv>>2); lane = s-row.
// Each wave reads HALF the x2 tile per kt (16 b128) and computes 4 heads
// per read (32 FMA / 12cy LDS read). q-index wave-uniform -> s_load. x2
// reg-staged prefetch as R3. Partial dots exchanged once via scp (4KB,
// aliased into dead tile); waves ch2==0 finish: wave-local max/sum
// butterflies, float4 e-write to etab, mls write. x3 prefetch issued
// before the final barrier (overlaps softmax).
// Phase B: wave = (head-group wv>>1, col-half wv&1); lane owns 4 cols
// (float4); 64 rows, 4-deep pipeline; disjoint float4 gp stores.
__global__ __launch_bounds__(512, 8) void k_attn(const float* __restrict__ x2,
                                                 const float* __restrict__ x3,
                                                 const float* __restrict__ w,
                                                 float* __restrict__ gp,
                                                 float* __restrict__ mls) {
    __shared__ __align__(16) char smem[64 * 33 * 16];   // 33.8 KB
    float4* tile = (float4*)smem;                       // x2 stage (phase A)
    float*  scp  = (float*)smem;                        // [hq][4][64] 4KB (post-tile alias)
    float*  etab = (float*)(smem + 8192);               // [row][20] 5KB (post-tile alias)

    const int b = blockIdx.y, ch = blockIdx.x;
    const int l = threadIdx.x & 63;
    const int wv = wave_id();          // 0..7
    const int hq  = wv & 3;            // head quad (phase A)
    const int ch2 = wv >> 2;           // c4 half (phase A)
    const int h0 = hq * 4;
    const int c4b = ch2 * 16;
    const int s0 = ch * 64;
    const float4* wp = (const float4*)(w + ((size_t)b * NH + h0) * DIN);
    const float4* x2f = (const float4*)x2 + ((size_t)b * SS + s0) * (DIN / 4);

    // ---- phase A: scores, heads h0..h0+3, c4-half c4b..c4b+15, lane = row ----
    const int srow = threadIdx.x >> 5;   // 0..15 (staging row base)
    const int sc4  = threadIdx.x & 31;   // 0..31 (staging col)
    float4 r0 = x2f[(size_t)(srow)      * 128 + sc4];
    float4 r1 = x2f[(size_t)(srow + 16) * 128 + sc4];
    float4 r2 = x2f[(size_t)(srow + 32) * 128 + sc4];
    float4 r3 = x2f[(size_t)(srow + 48) * 128 + sc4];
    float a0 = 0.f, a1 = 0.f, a2 = 0.f, a3 = 0.f;
    for (int kt = 0; kt < 4; ++kt) {
        __syncthreads();                    // prev compute done; tile free
        tile[(srow)      * 33 + sc4] = r0;  // vmcnt waits inserted here
        tile[(srow + 16) * 33 + sc4] = r1;
        tile[(srow + 32) * 33 + sc4] = r2;
        tile[(srow + 48) * 33 + sc4] = r3;
        __syncthreads();                    // tile ready
        if (kt < 3) {                       // issue kt+1 loads; land under compute
            const int kc = (kt + 1) * 32 + sc4;
            r0 = x2f[(size_t)(srow)      * 128 + kc];
            r1 = x2f[(size_t)(srow + 16) * 128 + kc];
            r2 = x2f[(size_t)(srow + 32) * 128 + kc];
            r3 = x2f[(size_t)(srow + 48) * 128 + kc];
        }
#pragma unroll 8
        for (int k = 0; k < 16; ++k) {
            const float4 x = tile[l * 33 + c4b + k];
            const float4 q0 = wp[      kt * 32 + c4b + k];   // uniform -> s_load
            const float4 q1 = wp[128 + kt * 32 + c4b + k];
            const float4 q2 = wp[256 + kt * 32 + c4b + k];
            const float4 q3 = wp[384 + kt * 32 + c4b + k];
            a0 += x.x * q0.x + x.y * q0.y + x.z * q0.z + x.w * q0.w;
            a1 += x.x * q1.x + x.y * q1.y + x.z * q1.z + x.w * q1.w;
            a2 += x.x * q2.x + x.y * q2.y + x.z * q2.z + x.w * q2.w;
            a3 += x.x * q3.x + x.y * q3.y + x.z * q3.z + x.w * q3.w;
        }
    }

    // partial-dot exchange: ch2==1 waves park partials in scp (tile dead)
    __syncthreads();
    if (ch2 == 1) {
        scp[(hq * 4 + 0) * 64 + l] = a0;
        scp[(hq * 4 + 1) * 64 + l] = a1;
        scp[(hq * 4 + 2) * 64 + l] = a2;
        scp[(hq * 4 + 3) * 64 + l] = a3;
    }
    __syncthreads();

    if (ch2 == 0) {
        a0 += scp[(hq * 4 + 0) * 64 + l];
        a1 += scp[(hq * 4 + 1) * 64 + l];
        a2 += scp[(hq * 4 + 2) * 64 + l];
        a3 += scp[(hq * 4 + 3) * 64 + l];
        const float sc0 = a0 * 0.125f, sc1 = a1 * 0.125f;
        const float sc2 = a2 * 0.125f, sc3 = a3 * 0.125f;
        float m0 = sc0, m1 = sc1, m2 = sc2, m3 = sc3;
#pragma unroll
        for (int off = 1; off < 64; off <<= 1) {
            m0 = fmaxf(m0, __shfl_xor(m0, off));
            m1 = fmaxf(m1, __shfl_xor(m1, off));
            m2 = fmaxf(m2, __shfl_xor(m2, off));
            m3 = fmaxf(m3, __shfl_xor(m3, off));
        }
        const float e0 = __expf(sc0 - m0), e1 = __expf(sc1 - m1);
        const float e2 = __expf(sc2 - m2), e3 = __expf(sc3 - m3);
        *(float4*)&etab[l * 20 + h0] = make_float4(e0, e1, e2, e3);
        float ls0 = e0, ls1 = e1, ls2 = e2, ls3 = e3;
#pragma unroll
        for (int off = 1; off < 64; off <<= 1) {
            ls0 += __shfl_xor(ls0, off);
            ls1 += __shfl_xor(ls1, off);
            ls2 += __shfl_xor(ls2, off);
            ls3 += __shfl_xor(ls3, off);
        }
        if (l == 0) {
            float* dst = mls + (((size_t)b * NCH + ch) * NH + h0) * 2;
            dst[0] = m0; dst[1] = ls0;
            dst[2] = m1; dst[3] = ls1;
            dst[4] = m2; dst[5] = ls2;
            dst[6] = m3; dst[7] = ls3;
        }
    }

    // ---- phase B: wave = (4-head group, 256-col half), lane = 4 cols ----
    const int colh = wv & 1;           // col half: 0,1
    const int h4 = (wv >> 1) * 4;      // head group base: 0,4,8,12
    const float4* x3f = (const float4*)(x3 + ((size_t)b * SS + s0) * DIN)
                        + colh * 64 + l;
    // issue prefetch BEFORE the barrier: latency overlaps softmax drain
    float4 p0 = x3f[0 * 128], p1 = x3f[1 * 128];
    float4 p2 = x3f[2 * 128], p3 = x3f[3 * 128];
    __syncthreads();   // etab visible to all waves

    float4 A0 = make_float4(0.f, 0.f, 0.f, 0.f);
    float4 A1 = make_float4(0.f, 0.f, 0.f, 0.f);
    float4 A2 = make_float4(0.f, 0.f, 0.f, 0.f);
    float4 A3 = make_float4(0.f, 0.f, 0.f, 0.f);
#pragma unroll 4
    for (int j = 0; j < 64; ++j) {
        const float4 xv = p0;
        p0 = p1; p1 = p2; p2 = p3;
        const int jn = (j + 4 < 64) ? (j + 4) : 63;
        p3 = x3f[(size_t)jn * 128];
        const float4 e4 = *(const float4*)&etab[j * 20 + h4];  // broadcast
        A0.x += e4.x * xv.x; A0.y += e4.x * xv.y; A0.z += e4.x * xv.z; A0.w += e4.x * xv.w;
        A1.x += e4.y * xv.x; A1.y += e4.y * xv.y; A1.z += e4.y * xv.z; A1.w += e4.y * xv.w;
        A2.x += e4.z * xv.x; A2.y += e4.z * xv.y; A2.z += e4.z * xv.z; A2.w += e4.z * xv.w;
        A3.x += e4.w * xv.x; A3.y += e4.w * xv.y; A3.z += e4.w * xv.z; A3.w += e4.w * xv.w;
    }

    // epilogue: direct float4 gp stores (disjoint head x col partition)
    float* gb = gp + ((size_t)(b * NCH + ch) * NH + h4) * DIN + colh * 256 + 4 * l;
    *(float4*)(gb + 0 * DIN) = A0;
    *(float4*)(gb + 1 * DIN) = A1;
    *(float4*)(gb + 2 * DIN) = A2;
    *(float4*)(gb + 3 * DIN) = A3;
}

// Flash combine: g[b*16+h][i] = sum_ch exp(m_ch-M)*gp_ch[i] / sum_ch exp(m_ch-M)*l_ch
// grid 256 (one per b,h pair), block 128; thread owns 4 i-cols (float4).
__global__ __launch_bounds__(128) void k_greduce2(const float* __restrict__ gp,
                                                  const float* __restrict__ mls,
                                                  float* __restrict__ g) {
    const int pair = blockIdx.x;      // b*16+h
    const int b = pair >> 4, h = pair & 15;
    const int t = threadIdx.x;        // 0..127, owns cols 4t..4t+3
    const float* mbase = mls + ((size_t)b * NCH * NH + h) * 2;  // stride NH*2/ch
    float M = -1e30f;
#pragma unroll 8
    for (int ch = 0; ch < NCH; ++ch)
        M = fmaxf(M, mbase[(size_t)ch * NH * 2]);   // uniform -> s_load
    float L = 0.f;
#pragma unroll 8
    for (int ch = 0; ch < NCH; ++ch)
        L += __expf(mbase[(size_t)ch * NH * 2] - M) * mbase[(size_t)ch * NH * 2 + 1];
    const float invL = 1.f / L;
    const float4* gpb = (const float4*)(gp + ((size_t)(b * NCH) * NH + h) * DIN) + t;
    float4 acc = make_float4(0.f, 0.f, 0.f, 0.f);
#pragma unroll 8
    for (int ch = 0; ch < NCH; ++ch) {
        const float f = __expf(mbase[(size_t)ch * NH * 2] - M);
        const float4 v = gpb[(size_t)ch * NH * (DIN / 4)];
        acc.x += f * v.x; acc.y += f * v.y; acc.z += f * v.z; acc.w += f * v.w;
    }
    acc.x *= invL; acc.y *= invL; acc.z *= invL; acc.w *= invL;
    ((float4*)(g + (size_t)pair * DIN))[t] = acc;
}

// av[b][h*64+l] (+)= sum_c G2[b*16+h][c]*Wv[c][h*64+l] over a 128-c chunk.
__global__ __launch_bounds__(256) void k_av_at(const float* __restrict__ G2,
                                               const float* __restrict__ Wv,
                                               float* __restrict__ av) {
    const int h = blockIdx.x;
    const int l = threadIdx.x & 63;
    const int wv = wave_id();
    const int c0 = blockIdx.y * 128 + wv * 32;
    float acc[16];
#pragma unroll
    for (int bb = 0; bb < 16; ++bb) acc[bb] = 0.f;
#pragma unroll 8
    for (int c = c0; c < c0 + 32; ++c) {
        const float wval = Wv[(size_t)c * DD + h * HD + l];  // coalesced
#pragma unroll
        for (int bb = 0; bb < 16; ++bb)
            acc[bb] += G2[((size_t)bb * NH + h) * DD + c] * wval;  // s_load
    }
    __shared__ float red[4][16][64];
#pragma unroll
    for (int bb = 0; bb < 16; ++bb) red[wv][bb][l] = acc[bb];
    __syncthreads();
#pragma unroll
    for (int k = 0; k < 4; ++k) {
        const int bb = wv + k * 4;
        float v = red[0][bb][l] + red[1][bb][l] + red[2][bb][l] + red[3][bb][l];
        atomicAdd(&av[(size_t)bb * DD + h * HD + l], v);
    }
}

extern "C" void kernel_launch(void* const* d_in, const int* in_sizes, int n_in,
                              void* d_out, int out_size, void* d_ws, size_t ws_size,
                              hipStream_t stream) {
    const float* x1  = (const float*)d_in[0];
    const float* x2  = (const float*)d_in[1];
    const float* x3  = (const float*)d_in[2];
    const float* We1 = (const float*)d_in[3];
    const float* be1 = (const float*)d_in[4];
    const float* We2 = (const float*)d_in[5];
    const float* be2 = (const float*)d_in[6];
    const float* Wq  = (const float*)d_in[7];
    const float* bq  = (const float*)d_in[8];
    const float* Wk  = (const float*)d_in[9];
    const float* bk  = (const float*)d_in[10];  // cancels in softmax (unused)
    const float* Wv  = (const float*)d_in[11];
    const float* bv  = (const float*)d_in[12];
    const float* Wo  = (const float*)d_in[13];
    const float* bo  = (const float*)d_in[14];
    (void)bk;
    float* out = (float*)d_out;

    char* ws = (char*)d_ws;
    size_t off = 0;
    auto alloc = [&](size_t bytes) -> void* {
        void* p = ws + off;
        off = (off + bytes + 255) & ~(size_t)255;
        return p;
    };
    float* We2t = (float*)alloc((size_t)DD * DIN * 4);  // [1024][512]
    float* WkT  = (float*)alloc((size_t)DD * DD * 4);   // [1024][1024]
    float* x1e  = (float*)alloc((size_t)BB * DD * 4);
    float* qb   = (float*)alloc((size_t)BB * DD * 4);
    float* u    = (float*)alloc((size_t)BB * NH * DD * 4);
    float* wv_  = (float*)alloc((size_t)BB * NH * DIN * 4);
    float* g    = (float*)alloc((size_t)BB * NH * DIN * 4);
    float* G2   = (float*)alloc((size_t)BB * NH * DD * 4);
    float* av   = (float*)alloc((size_t)BB * DD * 4);
    float* gp   = (float*)alloc((size_t)BB * NCH * NH * DIN * 4);  // 32MB
    float* mls  = (float*)alloc((size_t)BB * NCH * NH * 2 * 4);

    // prep: transposes + bias inits (one dispatch)
    k_prep<<<1552, 256, 0, stream>>>(We2, Wk, be1, bq, bv, bo,
                                     We2t, WkT, x1e, qb, av, out);
    // x1e += x1@We1   (K=512, KS=8 -> 128 blocks)
    k_bmv2<DIN, DD, 8, false><<<dim3(DD / 64, 1, 8), 256, 0, stream>>>(x1, We1, nullptr, x1e);
    // qb += x1e@Wq    (K=1024, KS=8 -> 128 blocks)
    k_bmv2<DD, DD, 8, false><<<dim3(DD / 64, 1, 8), 256, 0, stream>>>(x1e, Wq, nullptr, qb);
    k_u2<<<dim3(DD / 64, NH), 256, 0, stream>>>(qb, WkT, u);
    // w = u@We2t      (R=256 -> 128 blocks)
    k_bmv2<DD, DIN, 1, false><<<dim3(DIN / 64, BB * NH / 16, 1), 256, 0, stream>>>(u, We2t, nullptr, wv_);
    // fused scores + softmax + PV partials (1024 blocks x 8 waves = 32 waves/CU)
    k_attn<<<dim3(NCH, BB), 512, 0, stream>>>(x2, x3, wv_, gp, mls);
    k_greduce2<<<BB * NH, 128, 0, stream>>>(gp, mls, g);
    // G2 = g@We2+be2  (R=256 -> 256 blocks)
    k_bmv2<DIN, DD, 1, true><<<dim3(DD / 64, BB * NH / 16, 1), 256, 0, stream>>>(g, We2, be2, G2);
    k_av_at<<<dim3(NH, 8), 256, 0, stream>>>(G2, Wv, av);
    // out += av@Wo    (K=1024, KS=8 -> 128 blocks)
    k_bmv2<DD, DD, 8, false><<<dim3(DD / 64, 1, 8), 256, 0, stream>>>(av, Wo, nullptr, out);
}

// Round 5
// 453.627 us; speedup vs baseline: 1.0273x; 1.0273x over previous
//
#include <hip/hip_runtime.h>

// CrossAttention decode, algebraically collapsed (all fp32):
//   q[b,h,:]   = ((x1@We1+be1)@Wq+bq) head-sliced
//   u[b,h,c]   = sum_d WkT[h*64+d,c]*q[b,h,d]
//   w[b,h,i]   = sum_c u[b,h,c]*We2t[c,i]          (K-proj folded)
//   score[b,h,s] = x2[b,s,:].w[b,h,:]              (K-bias cancels in softmax)
//   a = softmax(score/8)
//   g[b,h,i]   = sum_s a[b,h,s]*x3[b,s,i]
//   G2[b,h,c]  = g@We2 + be2;  av = G2@Wv_h + bv;  out = av@Wo + bo
// R5 (this round): R1-R4 falsified occupancy / bytes-in-flight / LDS-pipe
// theories (4 variants, all ~104-113us, every pipe ~20%). Surviving model:
// per-CU outstanding-miss (L1 MSHR) cap -> delivered BW pinned at ~1.6TB/s
// regardless of wave count (cap is per-CU, explains all flat rounds; the
// 537MB reset fill at 86% peak shows stores don't hit this cap). Levers:
// (1) __builtin_nontemporal_load (nt) on x2/x3/gp streaming reads - tests
//     whether nt relaxes L1 miss tracking;
// (2) NCH 64->32 (128-row chunks, two 64-row tile passes in phase A with
//     cross-pass max merge): halves gp+mls round-trip (-48MB); at the
//     capped 1.6TB/s that alone is ~-25us even if (1) is flat.
// Base = R3 structure (best, 104us); R4's phase-A split reverted.
// Lessons: no per-element global atomics on hot paths; stride-33/pad-20 LDS
// conflict-free; occupancy 39->81% bought ~nothing (R2); harness reset
// (~170us) is fixed overhead inside the timing window.

#define DIN 512
#define DD  1024
#define NH  16
#define HD  64
#define BB  16
#define SS  4096
#define NCH 32   // s-chunks; schunk = 128

typedef float vf4 __attribute__((ext_vector_type(4)));

__device__ __forceinline__ float4 ldnt(const float4* p) {
    vf4 v = __builtin_nontemporal_load((const vf4*)p);
    return make_float4(v[0], v[1], v[2], v[3]);
}

__device__ __forceinline__ int wave_id() {
    return __builtin_amdgcn_readfirstlane((int)(threadIdx.x >> 6));
}

__device__ __forceinline__ void tile_transpose(const float* __restrict__ in,
                                               float* __restrict__ out,
                                               int R, int C, int rblk, int cblk) {
    __shared__ float tl[32][33];
    const int tx = threadIdx.x & 31, ty = threadIdx.x >> 5;  // ty 0..7
    const int c0 = cblk * 32, r0 = rblk * 32;
#pragma unroll
    for (int k = 0; k < 4; ++k)
        tl[ty + k * 8][tx] = in[(size_t)(r0 + ty + k * 8) * C + c0 + tx];
    __syncthreads();
#pragma unroll
    for (int k = 0; k < 4; ++k)
        out[(size_t)(c0 + ty + k * 8) * R + r0 + tx] = tl[tx][ty + k * 8];
}

// One fused prep dispatch: We2/Wk transposes + bias init of atomic targets.
__global__ __launch_bounds__(256) void k_prep(const float* __restrict__ We2,
                                              const float* __restrict__ Wk,
                                              const float* __restrict__ be1,
                                              const float* __restrict__ bq,
                                              const float* __restrict__ bv,
                                              const float* __restrict__ bo,
                                              float* __restrict__ We2t,
                                              float* __restrict__ WkT,
                                              float* __restrict__ x1e,
                                              float* __restrict__ qb,
                                              float* __restrict__ av,
                                              float* __restrict__ out) {
    const int bx = blockIdx.x;
    if (bx < 512) {
        tile_transpose(We2, We2t, DIN, DD, bx >> 5, bx & 31);
    } else if (bx < 1536) {
        const int lb = bx - 512;
        tile_transpose(Wk, WkT, DD, DD, lb >> 5, lb & 31);
    } else {
        const int b = bx - 1536;
#pragma unroll
        for (int k = 0; k < 4; ++k) {
            const int c = k * 256 + threadIdx.x;
            x1e[(size_t)b * DD + c] = be1[c];
            qb[(size_t)b * DD + c]  = bq[c];
            av[(size_t)b * DD + c]  = bv[c];
            out[(size_t)b * DD + c] = bo[c];
        }
    }
}

// out[r][c] (+)= sum_i in[r][i]*W[i][c] for 16 rows. grid (N/64, R/16, KS).
template <int K, int N, int KS, bool HASB>
__global__ __launch_bounds__(256) void k_bmv2(const float* __restrict__ in,
                                              const float* __restrict__ W,
                                              const float* __restrict__ bias,
                                              float* __restrict__ out) {
    const int l = threadIdx.x & 63;
    const int c = blockIdx.x * 64 + l;
    const int wv = wave_id();
    constexpr int KCH = K / KS;
    constexpr int SUB = KCH / 4;
    const float* inb = in + (size_t)blockIdx.y * 16 * K;  // uniform -> s_load
    float acc[16];
#pragma unroll
    for (int r = 0; r < 16; ++r) acc[r] = 0.f;
    const int i0 = blockIdx.z * KCH + wv * SUB;
#pragma unroll 8
    for (int i = i0; i < i0 + SUB; ++i) {
        const float wval = W[(size_t)i * N + c];  // coalesced 256B/wave
#pragma unroll
        for (int r = 0; r < 16; ++r) acc[r] += inb[(size_t)r * K + i] * wval;
    }
    __shared__ float red[4][16][64];
#pragma unroll
    for (int r = 0; r < 16; ++r) red[wv][r][l] = acc[r];
    __syncthreads();
#pragma unroll
    for (int k = 0; k < 4; ++k) {
        const int r = wv + k * 4;
        float v = red[0][r][l] + red[1][r][l] + red[2][r][l] + red[3][r][l];
        float* dst = out + ((size_t)blockIdx.y * 16 + r) * N + c;
        if (KS == 1) {
            if (HASB) v += bias[c];
            *dst = v;
        } else {
            atomicAdd(dst, v);
        }
    }
}

// u[b*16+h][c] = sum_d q[b][h*64+d]*WkT[h*64+d][c].  grid (1024/64, 16 h).
__global__ __launch_bounds__(256) void k_u2(const float* __restrict__ q,
                                            const float* __restrict__ WkT,
                                            float* __restrict__ u) {
    const int h = blockIdx.y;
    const int l = threadIdx.x & 63;
    const int c = blockIdx.x * 64 + l;
    const int wv = wave_id();
    float acc[16];
#pragma unroll
    for (int bb = 0; bb < 16; ++bb) acc[bb] = 0.f;
#pragma unroll 8
    for (int dk = 0; dk < 16; ++dk) {
        const int d = wv * 16 + dk;
        const float wval = WkT[(size_t)(h * HD + d) * DD + c];  // coalesced
#pragma unroll
        for (int bb = 0; bb < 16; ++bb)
            acc[bb] += q[(size_t)bb * DD + h * HD + d] * wval;  // s_load
    }
    __shared__ float red[4][16][64];
#pragma unroll
    for (int bb = 0; bb < 16; ++bb) red[wv][bb][l] = acc[bb];
    __syncthreads();
#pragma unroll
    for (int k = 0; k < 4; ++k) {
        const int bb = wv + k * 4;
        float v = red[0][bb][l] + red[1][bb][l] + red[2][bb][l] + red[3][bb][l];
        u[((size_t)bb * NH + h) * DD + c] = v;
    }
}

// Fused scores+softmax+PV: grid (NCH=32, 16 b), block 512 (8 waves).
// 128-row chunk as two 64-row tile passes (t=0,1). Phase A: wave wv owns
// heads 2wv..2wv+1, lane = row-in-half; x2 reg-staged NT prefetch (kt+1
// issued under kt's compute, t-boundary crossed by the kt==3 prefetch);
// per-head max merged across both halves, then one shfl-xor butterfly;
// e for both rows to pad-20 etab[128][20]; lsum = butterfly of (e0+e1).
// Phase B: wave = (head-group wv>>1, col-half wv&1); lane owns 4 cols
// (float4 NT); 128 rows, 4-deep pipeline; disjoint float4 gp stores.
__global__ __launch_bounds__(512, 8) void k_attn(const float* __restrict__ x2,
                                                 const float* __restrict__ x3,
                                                 const float* __restrict__ w,
                                                 float* __restrict__ gp,
                                                 float* __restrict__ mls) {
    __shared__ __align__(16) float4 tile[64 * 33];   // 33.8 KB x2 stage
    __shared__ __align__(16) float etab[128 * 20];   // 10 KB e-table [row][head]

    const int b = blockIdx.y, ch = blockIdx.x;
    const int l = threadIdx.x & 63;
    const int wv = wave_id();          // 0..7
    const int h0 = wv * 2;
    const int s0 = ch * 128;
    const float4* wp = (const float4*)(w + ((size_t)b * NH + h0) * DIN);
    const float4* x2f = (const float4*)x2 + ((size_t)b * SS + s0) * (DIN / 4);

    const int srow = threadIdx.x >> 5;   // 0..15 (staging row base)
    const int sc4  = threadIdx.x & 31;   // 0..31 (staging col)
    // prefetch t=0, kt=0
    float4 r0 = ldnt(&x2f[(size_t)(srow)      * 128 + sc4]);
    float4 r1 = ldnt(&x2f[(size_t)(srow + 16) * 128 + sc4]);
    float4 r2 = ldnt(&x2f[(size_t)(srow + 32) * 128 + sc4]);
    float4 r3 = ldnt(&x2f[(size_t)(srow + 48) * 128 + sc4]);
    float a00 = 0.f, a10 = 0.f;   // t=0: heads h0, h0+1
    float a01 = 0.f, a11 = 0.f;   // t=1

    // ---- phase A, t = 0 (rows s0..s0+63) ----
    for (int kt = 0; kt < 4; ++kt) {
        __syncthreads();                    // prev compute done; tile free
        tile[(srow)      * 33 + sc4] = r0;  // vmcnt waits inserted here
        tile[(srow + 16) * 33 + sc4] = r1;
        tile[(srow + 32) * 33 + sc4] = r2;
        tile[(srow + 48) * 33 + sc4] = r3;
        __syncthreads();                    // tile ready
        {   // prefetch: t0,kt+1 for kt<3; else t1,kt0 (crosses t boundary)
            const int rb = (kt < 3) ? 0 : 64;
            const int kc = ((kt < 3) ? (kt + 1) : 0) * 32 + sc4;
            r0 = ldnt(&x2f[(size_t)(rb + srow)      * 128 + kc]);
            r1 = ldnt(&x2f[(size_t)(rb + srow + 16) * 128 + kc]);
            r2 = ldnt(&x2f[(size_t)(rb + srow + 32) * 128 + kc]);
            r3 = ldnt(&x2f[(size_t)(rb + srow + 48) * 128 + kc]);
        }
#pragma unroll 8
        for (int c4 = 0; c4 < 32; ++c4) {
            const float4 x = tile[l * 33 + c4];
            const float4 q0 = wp[kt * 32 + c4];            // uniform -> s_load
            const float4 q1 = wp[128 + kt * 32 + c4];
            a00 += x.x * q0.x + x.y * q0.y + x.z * q0.z + x.w * q0.w;
            a10 += x.x * q1.x + x.y * q1.y + x.z * q1.z + x.w * q1.w;
        }
    }
    // ---- phase A, t = 1 (rows s0+64..s0+127) ----
    for (int kt = 0; kt < 4; ++kt) {
        __syncthreads();
        tile[(srow)      * 33 + sc4] = r0;
        tile[(srow + 16) * 33 + sc4] = r1;
        tile[(srow + 32) * 33 + sc4] = r2;
        tile[(srow + 48) * 33 + sc4] = r3;
        __syncthreads();
        if (kt < 3) {
            const int kc = (kt + 1) * 32 + sc4;
            r0 = ldnt(&x2f[(size_t)(64 + srow)      * 128 + kc]);
            r1 = ldnt(&x2f[(size_t)(64 + srow + 16) * 128 + kc]);
            r2 = ldnt(&x2f[(size_t)(64 + srow + 32) * 128 + kc]);
            r3 = ldnt(&x2f[(size_t)(64 + srow + 48) * 128 + kc]);
        }
#pragma unroll 8
        for (int c4 = 0; c4 < 32; ++c4) {
            const float4 x = tile[l * 33 + c4];
            const float4 q0 = wp[kt * 32 + c4];
            const float4 q1 = wp[128 + kt * 32 + c4];
            a01 += x.x * q0.x + x.y * q0.y + x.z * q0.z + x.w * q0.w;
            a11 += x.x * q1.x + x.y * q1.y + x.z * q1.z + x.w * q1.w;
        }
    }

    // per-head chunk max (both halves) + e + sum, all in-wave
    const float sc00 = a00 * 0.125f, sc10 = a10 * 0.125f;
    const float sc01 = a01 * 0.125f, sc11 = a11 * 0.125f;
    float m0 = fmaxf(sc00, sc01), m1 = fmaxf(sc10, sc11);
#pragma unroll
    for (int off = 1; off < 64; off <<= 1) {
        m0 = fmaxf(m0, __shfl_xor(m0, off));
        m1 = fmaxf(m1, __shfl_xor(m1, off));
    }
    const float e00 = __expf(sc00 - m0), e01 = __expf(sc01 - m0);
    const float e10 = __expf(sc10 - m1), e11 = __expf(sc11 - m1);
    etab[l * 20 + h0]            = e00;
    etab[l * 20 + h0 + 1]        = e10;
    etab[(64 + l) * 20 + h0]     = e01;
    etab[(64 + l) * 20 + h0 + 1] = e11;
    float ls0 = e00 + e01, ls1 = e10 + e11;
#pragma unroll
    for (int off = 1; off < 64; off <<= 1) {
        ls0 += __shfl_xor(ls0, off);
        ls1 += __shfl_xor(ls1, off);
    }
    if (l == 0) {
        float* dst = mls + (((size_t)b * NCH + ch) * NH + h0) * 2;
        dst[0] = m0; dst[1] = ls0;
        dst[2] = m1; dst[3] = ls1;
    }

    // ---- phase B: wave = (4-head group, 256-col half), lane = 4 cols ----
    const int colh = wv & 1;           // col half: 0,1
    const int h4 = (wv >> 1) * 4;      // head group base: 0,4,8,12
    const float4* x3f = (const float4*)(x3 + ((size_t)b * SS + s0) * DIN)
                        + colh * 64 + l;
    // issue prefetch BEFORE the barrier: latency overlaps softmax drain
    float4 p0 = ldnt(&x3f[0 * 128]), p1 = ldnt(&x3f[1 * 128]);
    float4 p2 = ldnt(&x3f[2 * 128]), p3 = ldnt(&x3f[3 * 128]);
    __syncthreads();   // etab visible to all waves

    float4 A0 = make_float4(0.f, 0.f, 0.f, 0.f);
    float4 A1 = make_float4(0.f, 0.f, 0.f, 0.f);
    float4 A2 = make_float4(0.f, 0.f, 0.f, 0.f);
    float4 A3 = make_float4(0.f, 0.f, 0.f, 0.f);
#pragma unroll 4
    for (int j = 0; j < 128; ++j) {
        const float4 xv = p0;
        p0 = p1; p1 = p2; p2 = p3;
        const int jn = (j + 4 < 128) ? (j + 4) : 127;
        p3 = ldnt(&x3f[(size_t)jn * 128]);
        const float4 e4 = *(const float4*)&etab[j * 20 + h4];  // broadcast
        A0.x += e4.x * xv.x; A0.y += e4.x * xv.y; A0.z += e4.x * xv.z; A0.w += e4.x * xv.w;
        A1.x += e4.y * xv.x; A1.y += e4.y * xv.y; A1.z += e4.y * xv.z; A1.w += e4.y * xv.w;
        A2.x += e4.z * xv.x; A2.y += e4.z * xv.y; A2.z += e4.z * xv.z; A2.w += e4.z * xv.w;
        A3.x += e4.w * xv.x; A3.y += e4.w * xv.y; A3.z += e4.w * xv.z; A3.w += e4.w * xv.w;
    }

    // epilogue: direct float4 gp stores (disjoint head x col partition)
    float* gb = gp + ((size_t)(b * NCH + ch) * NH + h4) * DIN + colh * 256 + 4 * l;
    *(float4*)(gb + 0 * DIN) = A0;
    *(float4*)(gb + 1 * DIN) = A1;
    *(float4*)(gb + 2 * DIN) = A2;
    *(float4*)(gb + 3 * DIN) = A3;
}

// Flash combine: g[b*16+h][i] = sum_ch exp(m_ch-M)*gp_ch[i] / sum_ch exp(m_ch-M)*l_ch
// grid 256 (one per b,h pair), block 128; thread owns 4 i-cols (float4, NT).
__global__ __launch_bounds__(128) void k_greduce2(const float* __restrict__ gp,
                                                  const float* __restrict__ mls,
                                                  float* __restrict__ g) {
    const int pair = blockIdx.x;      // b*16+h
    const int b = pair >> 4, h = pair & 15;
    const int t = threadIdx.x;        // 0..127, owns cols 4t..4t+3
    const float* mbase = mls + ((size_t)b * NCH * NH + h) * 2;  // stride NH*2/ch
    float M = -1e30f;
#pragma unroll 8
    for (int ch = 0; ch < NCH; ++ch)
        M = fmaxf(M, mbase[(size_t)ch * NH * 2]);   // uniform -> s_load
    float L = 0.f;
#pragma unroll 8
    for (int ch = 0; ch < NCH; ++ch)
        L += __expf(mbase[(size_t)ch * NH * 2] - M) * mbase[(size_t)ch * NH * 2 + 1];
    const float invL = 1.f / L;
    const float4* gpb = (const float4*)(gp + ((size_t)(b * NCH) * NH + h) * DIN) + t;
    float4 acc = make_float4(0.f, 0.f, 0.f, 0.f);
#pragma unroll 8
    for (int ch = 0; ch < NCH; ++ch) {
        const float f = __expf(mbase[(size_t)ch * NH * 2] - M);
        const float4 v = ldnt(&gpb[(size_t)ch * NH * (DIN / 4)]);
        acc.x += f * v.x; acc.y += f * v.y; acc.z += f * v.z; acc.w += f * v.w;
    }
    acc.x *= invL; acc.y *= invL; acc.z *= invL; acc.w *= invL;
    ((float4*)(g + (size_t)pair * DIN))[t] = acc;
}

// av[b][h*64+l] (+)= sum_c G2[b*16+h][c]*Wv[c][h*64+l] over a 128-c chunk.
__global__ __launch_bounds__(256) void k_av_at(const float* __restrict__ G2,
                                               const float* __restrict__ Wv,
                                               float* __restrict__ av) {
    const int h = blockIdx.x;
    const int l = threadIdx.x & 63;
    const int wv = wave_id();
    const int c0 = blockIdx.y * 128 + wv * 32;
    float acc[16];
#pragma unroll
    for (int bb = 0; bb < 16; ++bb) acc[bb] = 0.f;
#pragma unroll 8
    for (int c = c0; c < c0 + 32; ++c) {
        const float wval = Wv[(size_t)c * DD + h * HD + l];  // coalesced
#pragma unroll
        for (int bb = 0; bb < 16; ++bb)
            acc[bb] += G2[((size_t)bb * NH + h) * DD + c] * wval;  // s_load
    }
    __shared__ float red[4][16][64];
#pragma unroll
    for (int bb = 0; bb < 16; ++bb) red[wv][bb][l] = acc[bb];
    __syncthreads();
#pragma unroll
    for (int k = 0; k < 4; ++k) {
        const int bb = wv + k * 4;
        float v = red[0][bb][l] + red[1][bb][l] + red[2][bb][l] + red[3][bb][l];
        atomicAdd(&av[(size_t)bb * DD + h * HD + l], v);
    }
}

extern "C" void kernel_launch(void* const* d_in, const int* in_sizes, int n_in,
                              void* d_out, int out_size, void* d_ws, size_t ws_size,
                              hipStream_t stream) {
    const float* x1  = (const float*)d_in[0];
    const float* x2  = (const float*)d_in[1];
    const float* x3  = (const float*)d_in[2];
    const float* We1 = (const float*)d_in[3];
    const float* be1 = (const float*)d_in[4];
    const float* We2 = (const float*)d_in[5];
    const float* be2 = (const float*)d_in[6];
    const float* Wq  = (const float*)d_in[7];
    const float* bq  = (const float*)d_in[8];
    const float* Wk  = (const float*)d_in[9];
    const float* bk  = (const float*)d_in[10];  // cancels in softmax (unused)
    const float* Wv  = (const float*)d_in[11];
    const float* bv  = (const float*)d_in[12];
    const float* Wo  = (const float*)d_in[13];
    const float* bo  = (const float*)d_in[14];
    (void)bk;
    float* out = (float*)d_out;

    char* ws = (char*)d_ws;
    size_t off = 0;
    auto alloc = [&](size_t bytes) -> void* {
        void* p = ws + off;
        off = (off + bytes + 255) & ~(size_t)255;
        return p;
    };
    float* We2t = (float*)alloc((size_t)DD * DIN * 4);  // [1024][512]
    float* WkT  = (float*)alloc((size_t)DD * DD * 4);   // [1024][1024]
    float* x1e  = (float*)alloc((size_t)BB * DD * 4);
    float* qb   = (float*)alloc((size_t)BB * DD * 4);
    float* u    = (float*)alloc((size_t)BB * NH * DD * 4);
    float* wv_  = (float*)alloc((size_t)BB * NH * DIN * 4);
    float* g    = (float*)alloc((size_t)BB * NH * DIN * 4);
    float* G2   = (float*)alloc((size_t)BB * NH * DD * 4);
    float* av   = (float*)alloc((size_t)BB * DD * 4);
    float* gp   = (float*)alloc((size_t)BB * NCH * NH * DIN * 4);  // 16MB
    float* mls  = (float*)alloc((size_t)BB * NCH * NH * 2 * 4);

    // prep: transposes + bias inits (one dispatch)
    k_prep<<<1552, 256, 0, stream>>>(We2, Wk, be1, bq, bv, bo,
                                     We2t, WkT, x1e, qb, av, out);
    // x1e += x1@We1   (K=512, KS=8 -> 128 blocks)
    k_bmv2<DIN, DD, 8, false><<<dim3(DD / 64, 1, 8), 256, 0, stream>>>(x1, We1, nullptr, x1e);
    // qb += x1e@Wq    (K=1024, KS=8 -> 128 blocks)
    k_bmv2<DD, DD, 8, false><<<dim3(DD / 64, 1, 8), 256, 0, stream>>>(x1e, Wq, nullptr, qb);
    k_u2<<<dim3(DD / 64, NH), 256, 0, stream>>>(qb, WkT, u);
    // w = u@We2t      (R=256 -> 128 blocks)
    k_bmv2<DD, DIN, 1, false><<<dim3(DIN / 64, BB * NH / 16, 1), 256, 0, stream>>>(u, We2t, nullptr, wv_);
    // fused scores + softmax + PV partials (512 blocks x 8 waves)
    k_attn<<<dim3(NCH, BB), 512, 0, stream>>>(x2, x3, wv_, gp, mls);
    k_greduce2<<<BB * NH, 128, 0, stream>>>(gp, mls, g);
    // G2 = g@We2+be2  (R=256 -> 256 blocks)
    k_bmv2<DIN, DD, 1, true><<<dim3(DD / 64, BB * NH / 16, 1), 256, 0, stream>>>(g, We2, be2, G2);
    k_av_at<<<dim3(NH, 8), 256, 0, stream>>>(G2, Wv, av);
    // out += av@Wo    (K=1024, KS=8 -> 128 blocks)
    k_bmv2<DD, DD, 8, false><<<dim3(DD / 64, 1, 8), 256, 0, stream>>>(av, Wo, nullptr, out);
}